// Round 1
// baseline (23.636 us; speedup 1.0000x reference)
//
#include <hip/hip_runtime.h>
#include <cmath>

#define E_EXPERTS 16
#define D_DIM 2048
#define H_DIM 2048

// ---------------------------------------------------------------------------
// Kernel 1: gating. One block, 16 waves (1024 threads). Wave w computes
// logits[w] = dot(Wg[w], x) + bg[w]. Thread 0 then does softmax + top-2 +
// gate normalization serially over the 16 logits (trivial) and writes
// tkg[2] (float) and idx[2] (int) to the workspace.
// ---------------------------------------------------------------------------
__global__ __launch_bounds__(1024) void gate_kernel(
    const float* __restrict__ Wg, const float* __restrict__ bg,
    const float* __restrict__ x, float* __restrict__ tkg,
    int* __restrict__ idx) {
    __shared__ float slog[E_EXPERTS];
    const int wave = threadIdx.x >> 6;   // 0..15 = expert
    const int lane = threadIdx.x & 63;

    const float4* wrow = (const float4*)(Wg + (size_t)wave * D_DIM);
    const float4* xv   = (const float4*)x;

    float acc = 0.f;
#pragma unroll
    for (int i = 0; i < D_DIM / 4 / 64; ++i) {   // 8 iters
        float4 w  = wrow[lane + i * 64];
        float4 xx = xv[lane + i * 64];
        acc += w.x * xx.x + w.y * xx.y + w.z * xx.z + w.w * xx.w;
    }
#pragma unroll
    for (int off = 32; off; off >>= 1) acc += __shfl_down(acc, off, 64);
    if (lane == 0) slog[wave] = acc + bg[wave];
    __syncthreads();

    if (threadIdx.x == 0) {
        float m = -1e30f;
#pragma unroll
        for (int e = 0; e < E_EXPERTS; ++e) m = fmaxf(m, slog[e]);
        float p[E_EXPERTS];
        float s = 0.f;
#pragma unroll
        for (int e = 0; e < E_EXPERTS; ++e) { p[e] = __expf(slog[e] - m); s += p[e]; }
        // top-1 (first occurrence on ties, matching lax.top_k)
        int i0 = 0; float v0 = p[0];
#pragma unroll
        for (int e = 1; e < E_EXPERTS; ++e) if (p[e] > v0) { v0 = p[e]; i0 = e; }
        // top-2
        int i1 = -1; float v1 = -1.f;
#pragma unroll
        for (int e = 0; e < E_EXPERTS; ++e) {
            if (e == i0) continue;
            if (p[e] > v1) { v1 = p[e]; i1 = e; }
        }
        float g0 = v0 / s, g1 = v1 / s;
        float denom = g0 + g1 + 1e-6f;
        tkg[0] = g0 / denom;
        tkg[1] = g1 / denom;
        idx[0] = i0;
        idx[1] = i1;
    }
}

// ---------------------------------------------------------------------------
// Kernel 2: h[k][r] = tanh(dot(W1[idx[k]][r], x) + b1[idx[k]][r]).
// One wave per (k, r): 2*2048 = 4096 waves, 256-thread blocks (4 waves).
// Coalesced float4 loads of the weight row; x served from cache.
// ---------------------------------------------------------------------------
__global__ __launch_bounds__(256) void h_kernel(
    const float* __restrict__ W1, const float* __restrict__ b1,
    const float* __restrict__ x, const int* __restrict__ idx,
    float* __restrict__ h) {
    const int gwave = (blockIdx.x * 256 + threadIdx.x) >> 6;  // 0..4095
    const int lane  = threadIdx.x & 63;
    const int k = gwave >> 11;        // expert slot 0/1
    const int r = gwave & (H_DIM - 1);
    const int e = idx[k];

    const float4* wrow = (const float4*)(W1 + ((size_t)e * H_DIM + r) * D_DIM);
    const float4* xv   = (const float4*)x;

    float acc = 0.f;
#pragma unroll
    for (int i = 0; i < D_DIM / 4 / 64; ++i) {   // 8 iters
        float4 w  = wrow[lane + i * 64];
        float4 xx = xv[lane + i * 64];
        acc += w.x * xx.x + w.y * xx.y + w.z * xx.z + w.w * xx.w;
    }
#pragma unroll
    for (int off = 32; off; off >>= 1) acc += __shfl_down(acc, off, 64);
    if (lane == 0) h[k * H_DIM + r] = tanhf(acc + b1[(size_t)e * H_DIM + r]);
}

// ---------------------------------------------------------------------------
// Kernel 3: out[o] = tkg0*(dot(W2[e0][o], h0) + b2[e0][o])
//                  + tkg1*(dot(W2[e1][o], h1) + b2[e1][o]).
// One wave per output element o (2048 waves); both experts fused in-wave.
// ---------------------------------------------------------------------------
__global__ __launch_bounds__(256) void out_kernel(
    const float* __restrict__ W2, const float* __restrict__ b2,
    const float* __restrict__ h, const int* __restrict__ idx,
    const float* __restrict__ tkg, float* __restrict__ out) {
    const int o    = (blockIdx.x * 256 + threadIdx.x) >> 6;  // 0..2047
    const int lane = threadIdx.x & 63;
    const int e0 = idx[0], e1 = idx[1];

    const float4* r0 = (const float4*)(W2 + ((size_t)e0 * H_DIM + o) * H_DIM);
    const float4* r1 = (const float4*)(W2 + ((size_t)e1 * H_DIM + o) * H_DIM);
    const float4* h0 = (const float4*)h;
    const float4* h1 = (const float4*)(h + H_DIM);

    float a0 = 0.f, a1 = 0.f;
#pragma unroll
    for (int i = 0; i < H_DIM / 4 / 64; ++i) {   // 8 iters
        float4 w0 = r0[lane + i * 64];
        float4 x0 = h0[lane + i * 64];
        a0 += w0.x * x0.x + w0.y * x0.y + w0.z * x0.z + w0.w * x0.w;
        float4 w1 = r1[lane + i * 64];
        float4 x1 = h1[lane + i * 64];
        a1 += w1.x * x1.x + w1.y * x1.y + w1.z * x1.z + w1.w * x1.w;
    }
#pragma unroll
    for (int off = 32; off; off >>= 1) {
        a0 += __shfl_down(a0, off, 64);
        a1 += __shfl_down(a1, off, 64);
    }
    if (lane == 0) {
        float eo0 = a0 + b2[(size_t)e0 * H_DIM + o];
        float eo1 = a1 + b2[(size_t)e1 * H_DIM + o];
        out[o] = tkg[0] * eo0 + tkg[1] * eo1;
    }
}

extern "C" void kernel_launch(void* const* d_in, const int* in_sizes, int n_in,
                              void* d_out, int out_size, void* d_ws, size_t ws_size,
                              hipStream_t stream) {
    const float* x  = (const float*)d_in[0];
    const float* Wg = (const float*)d_in[1];
    const float* bg = (const float*)d_in[2];
    const float* W1 = (const float*)d_in[3];
    const float* b1 = (const float*)d_in[4];
    const float* W2 = (const float*)d_in[5];
    const float* b2 = (const float*)d_in[6];
    float* out = (float*)d_out;

    // workspace layout: [0..1] tkg floats, [2..3] idx ints, [16..] h[2][2048]
    float* ws_f = (float*)d_ws;
    float* tkg  = ws_f;
    int*   idx  = ((int*)d_ws) + 2;
    float* h    = ws_f + 16;

    gate_kernel<<<1, 1024, 0, stream>>>(Wg, bg, x, tkg, idx);
    h_kernel<<<(2 * H_DIM) / 4, 256, 0, stream>>>(W1, b1, x, idx, h);
    out_kernel<<<H_DIM / 4, 256, 0, stream>>>(W2, b2, h, idx, tkg, out);
}